// Round 2
// baseline (860.635 us; speedup 1.0000x reference)
//
#include <hip/hip_runtime.h>
#include <cstdint>
#include <cstddef>

#define B_  256
#define T_  128

constexpr float MU_F      = 0.1f;
constexpr float REG_FAC_F = (float)(1.6 * 1.6 - 1.0);   // 1.56

// ---- staging buffer layout (float offsets) ----
#define OF_FX   0
#define OF_FU   144
#define OF_FXX  192
#define OF_FXU  1920
#define OF_FUU  2496
#define OF_QXX  2688
#define OF_QXU  2832
#define OF_QUU  2880
#define OF_QX   2896
#define OF_QU   2908
#define OF_CX   2912
#define OF_CU   2984
#define OF_C    3008
#define OF_S    3014
#define STG_N   3020

// ---- output layout (float offsets into d_out) ----
#define O_KU    0
#define O_KUBIG 131072
#define O_KS    1703936
#define O_KSBIG 1900544
#define O_DV    4259840
#define O_OPT   4260352
#define O_VX    4260353
#define O_VXX   4263425

__device__ __forceinline__ void gl_lds16(const float* g, float* l) {
    __builtin_amdgcn_global_load_lds((const __attribute__((address_space(1))) void*)g,
                                     (__attribute__((address_space(3))) void*)l, 16, 0, 0);
}
__device__ __forceinline__ void gl_lds4(const float* g, float* l) {
    __builtin_amdgcn_global_load_lds((const __attribute__((address_space(1))) void*)g,
                                     (__attribute__((address_space(3))) void*)l, 4, 0, 0);
}
__device__ __forceinline__ void wait_vm0() {
    asm volatile("s_waitcnt vmcnt(0)" ::: "memory");
}

__global__ __launch_bounds__(64) void ddp_backward(
    const float* __restrict__ qx,  const float* __restrict__ qu,
    const float* __restrict__ qxx, const float* __restrict__ qxu,
    const float* __restrict__ quu, const float* __restrict__ fx,
    const float* __restrict__ fu,  const float* __restrict__ fxx,
    const float* __restrict__ fxu, const float* __restrict__ fuu,
    const float* __restrict__ cx,  const float* __restrict__ cu,
    const float* __restrict__ c_,  const float* __restrict__ s_,
    const float* __restrict__ px,  const float* __restrict__ pxx,
    float* __restrict__ out, float* __restrict__ ws)
{
    const int lane = threadIdx.x;    // 0..63, one wave per block
    const int b    = blockIdx.x;

    __shared__ float stg[2][STG_N];
    __shared__ float sVx[12], sVxx[144];
    __shared__ float sfxV[144], sfuV[48];
    __shared__ float sQxx2[144], stQux[48], sGuu[16];
    __shared__ float sQxb[12], sQub[4], sQu[4], sQx2[12];
    __shared__ float sr[6], scinv[6], ssc[6], sscr[6];
    __shared__ float sKu[48], sku[4];
    __shared__ float sErr[2];

    // per-lane accumulators carried in registers across the t-loop
    float accDV0 = 0.f, accDV1 = 0.f, accQE = 0.f, accME = 0.f;

    const float* srcs[14] = {qx, qu, qxx, qxu, quu, fx, fu, fxx, fxu, fuu, cx, cu, c_, s_};

    auto stage_all = [&](float* dst, int tt) {
        const size_t bt = (size_t)b * T_ + tt;
        constexpr int ch_arr[22]  = {5,6,7,7,7,7,7,7,7,8,8,8,9,2,3,4,0,1,10,11,12,13};
        constexpr int ch_goff[22] = {0,0,0,256,512,768,1024,1280,1536,0,256,512,0,0,0,0,0,0,0,0,0,0};
        constexpr int ch_loff[22] = {OF_FX, OF_FU,
                                     OF_FXX, OF_FXX+256, OF_FXX+512, OF_FXX+768,
                                     OF_FXX+1024, OF_FXX+1280, OF_FXX+1536,
                                     OF_FXU, OF_FXU+256, OF_FXU+512,
                                     OF_FUU, OF_QXX, OF_QXU, OF_QUU, OF_QX, OF_QU,
                                     OF_CX, OF_CU, OF_C, OF_S};
        constexpr int ch_nb[22]   = {576,192,1024,1024,1024,1024,1024,1024,768,
                                     1024,1024,256,768,576,192,64,48,16,288,96,24,24};
        constexpr int sl[14]      = {12,4,144,48,16,144,48,1728,576,192,72,24,6,6};
        #pragma unroll
        for (int ci = 0; ci < 22; ++ci) {
            const float* g = srcs[ch_arr[ci]] + bt * (size_t)sl[ch_arr[ci]] + ch_goff[ci];
            float* l = dst + ch_loff[ci];
            if ((ch_nb[ci] & 15) == 0) {
                if (lane * 16 < ch_nb[ci]) gl_lds16(g + lane * 4, l);
            } else {
                if (lane * 4  < ch_nb[ci]) gl_lds4 (g + lane,     l);
            }
        }
    };

    // ---------- prologue ----------
    for (int e = lane; e < 144; e += 64) sVxx[e] = pxx[(size_t)b * 144 + e];
    if (lane < 12) sVx[lane] = px[(size_t)b * 12 + lane];
    stage_all(stg[0], T_ - 1);
    wait_vm0();
    __syncthreads();

    int cur = 0;
    for (int t = T_ - 1; t >= 0; --t) {
        const float* S = stg[cur];
        if (t > 0) stage_all(stg[cur ^ 1], t - 1);
        const size_t bt = (size_t)b * T_ + t;

        // ================= Stage A: fxV(144), fuV(48) + scalars + Qxb/Qub =================
        {
            const float* wp; int wss; float* op; int k0;
            if (lane < 48) {
                const int i = lane >> 2; k0 = (lane & 3) * 3;
                wp = S + OF_FX + i; wss = 12; op = sfxV + i * 12 + k0;
            } else {
                const int a = (lane - 48) >> 2; k0 = ((lane - 48) & 3) * 3;
                wp = S + OF_FU + a; wss = 4;  op = sfuV + a * 12 + k0;
            }
            float a0 = 0.f, a1 = 0.f, a2 = 0.f;
            #pragma unroll
            for (int m = 0; m < 12; ++m) {
                const float w = wp[m * wss];
                const float* vp = sVxx + m * 12 + k0;
                a0 += w * vp[0]; a1 += w * vp[1]; a2 += w * vp[2];
            }
            op[0] = a0; op[1] = a1; op[2] = a2;
        }
        if (lane < 6) {
            const int k = lane;
            const float cc = S[OF_C + k], sv = S[OF_S + k];
            const float r  = sv * cc + MU_F;
            const float ci = 1.0f / cc;
            sr[k] = r; scinv[k] = ci; ssc[k] = sv * ci; sscr[k] = ci * r;
        } else if (lane < 22) {
            const float* cp; int cs; const float* fp; int fs; float bias; float* o;
            if (lane < 18) { const int i = lane - 6;  cp = S + OF_CX + i; cs = 12; fp = S + OF_FX + i; fs = 12; bias = S[OF_QX + i]; o = sQxb + i; }
            else           { const int a = lane - 18; cp = S + OF_CU + a; cs = 4;  fp = S + OF_FU + a; fs = 4;  bias = S[OF_QU + a]; o = sQub + a; }
            float acc = bias;
            #pragma unroll
            for (int k = 0; k < 6; ++k)  acc += cp[k * cs] * S[OF_S + k];
            #pragma unroll
            for (int m = 0; m < 12; ++m) acc += fp[m * fs] * sVx[m];
            *o = acc;
        }
        __syncthreads();

        // ================= Stage B': corrected Q quantities =================
        {
            const float *wp; int wss; const float *op; int osk, osd;
            const float *pp; int pss, psd; const float *up; int uss;
            const float *vp; const float *bp; int bsd; float *outp;
            if (lane < 48) {
                const int i = lane >> 2, j0 = (lane & 3) * 3;
                wp = sfxV + i * 12;           wss = 1;
                op = S + OF_FX + j0;          osk = 12; osd = 1;
                pp = S + OF_FXX + i * 12 + j0; pss = 144; psd = 1;
                up = S + OF_CX + i;           uss = 12;
                vp = S + OF_CX + j0;
                bp = S + OF_QXX + i * 12 + j0; bsd = 1;
                outp = sQxx2 + i * 12 + j0;
            } else {
                const int a = (lane - 48) >> 2, i0 = ((lane - 48) & 3) * 3;
                wp = S + OF_FU + a;           wss = 4;
                op = sfxV + i0 * 12;          osk = 1;  osd = 12;
                pp = S + OF_FXU + i0 * 4 + a; pss = 48; psd = 4;
                up = S + OF_CU + a;           uss = 4;
                vp = S + OF_CX + i0;
                bp = S + OF_QXU + i0 * 4 + a; bsd = 4;
                outp = stQux + a * 12 + i0;
            }
            float e0 = bp[0], e1 = bp[bsd], e2 = bp[2 * bsd];
            #pragma unroll
            for (int k = 0; k < 12; ++k) {
                const float w = wp[k * wss];
                const float* o = op + k * osk;
                e0 += w * o[0]; e1 += w * o[osd]; e2 += w * o[2 * osd];
            }
            #pragma unroll
            for (int s2 = 0; s2 < 12; ++s2) {
                const float v = sVx[s2];
                const float* p = pp + s2 * pss;
                e0 += v * p[0]; e1 += v * p[psd]; e2 += v * p[2 * psd];
            }
            #pragma unroll
            for (int k = 0; k < 6; ++k) {
                const float tt = ssc[k] * up[k * uss];
                const float* v = vp + k * 12;
                e0 -= tt * v[0]; e1 -= tt * v[1]; e2 -= tt * v[2];
            }
            outp[0] = e0; outp[1] = e1; outp[2] = e2;
        }
        if (lane < 16) {  // Guu = Quu_raw - cuSCcu (pre-symmetrization)
            const int a = lane >> 2, b2 = lane & 3;
            float acc = S[OF_QUU + lane];
            #pragma unroll
            for (int k = 0; k < 12; ++k)  acc += sfuV[a * 12 + k] * S[OF_FU + k * 4 + b2];
            #pragma unroll
            for (int s2 = 0; s2 < 12; ++s2) acc += sVx[s2] * S[OF_FUU + s2 * 16 + lane];
            #pragma unroll
            for (int k = 0; k < 6; ++k)   acc -= ssc[k] * S[OF_CU + k * 4 + a] * S[OF_CU + k * 4 + b2];
            sGuu[lane] = acc;
        } else if (lane < 32) {  // Qu (16..19), Qx2 (20..31)
            const float* cp; int cs; float bias; float* o;
            if (lane < 20) { const int a = lane - 16; cp = S + OF_CU + a; cs = 4;  bias = sQub[a]; o = sQu + a; }
            else           { const int i = lane - 20; cp = S + OF_CX + i; cs = 12; bias = sQxb[i]; o = sQx2 + i; }
            float acc = bias;
            #pragma unroll
            for (int k = 0; k < 6; ++k) acc -= cp[k * cs] * sscr[k];
            *o = acc;
        }
        __syncthreads();

        // ================= Stage D: Quu2/M4 (regs), LU, 13-RHS solve, K outputs =================
        float q2v[16];
        {
            float m4[16];
            #pragma unroll
            for (int e = 0; e < 16; ++e) {
                const int a = e >> 2, b2 = e & 3;
                const float g = 0.5f * (sGuu[e] + sGuu[b2 * 4 + a]);
                q2v[e] = g;
                m4[e]  = g + S[OF_QUU + e] * REG_FAC_F;
            }
            const float i0  = 1.0f / m4[0];
            const float l10 = m4[4] * i0, l20 = m4[8] * i0, l30 = m4[12] * i0;
            float a11 = m4[5]  - l10 * m4[1], a12 = m4[6]  - l10 * m4[2], a13 = m4[7]  - l10 * m4[3];
            float a21 = m4[9]  - l20 * m4[1], a22 = m4[10] - l20 * m4[2], a23 = m4[11] - l20 * m4[3];
            float a31 = m4[13] - l30 * m4[1], a32 = m4[14] - l30 * m4[2], a33 = m4[15] - l30 * m4[3];
            const float i1  = 1.0f / a11;
            const float l21 = a21 * i1, l31 = a31 * i1;
            a22 -= l21 * a12; a23 -= l21 * a13;
            a32 -= l31 * a12; a33 -= l31 * a13;
            const float i2  = 1.0f / a22;
            const float l32 = a32 * i2;
            a33 -= l32 * a23;

            if (lane < 13) {
                const int ii = (lane == 0) ? 0 : (lane - 1);
                float r0, r1, r2, r3;
                if (lane == 0) { r0 = sQu[0]; r1 = sQu[1]; r2 = sQu[2]; r3 = sQu[3]; }
                else { r0 = stQux[ii]; r1 = stQux[12 + ii]; r2 = stQux[24 + ii]; r3 = stQux[36 + ii]; }
                const float y0 = r0;
                const float y1 = r1 - l10 * y0;
                const float y2 = r2 - l20 * y0 - l21 * y1;
                const float y3 = r3 - l30 * y0 - l31 * y1 - l32 * y2;
                float x3 = y3 / a33;
                float x2 = (y2 - a23 * x3) * i2;
                float x1 = (y1 - a12 * x2 - a13 * x3) * i1;
                float x0 = (y0 - m4[1] * x1 - m4[2] * x2 - m4[3] * x3) * i0;
                x0 = -x0; x1 = -x1; x2 = -x2; x3 = -x3;

                const int gst = (lane == 0) ? 1 : 12;
                float* lK = (lane == 0) ? sku : (sKu + ii);
                lK[0] = x0; lK[gst] = x1; lK[2 * gst] = x2; lK[3 * gst] = x3;
                float* gK = (lane == 0) ? (out + O_KU + bt * 4) : (out + O_KUBIG + bt * 48 + ii);
                gK[0] = x0; gK[gst] = x1; gK[2 * gst] = x2; gK[3 * gst] = x3;

                const float* w1p = (lane == 0) ? scinv : ssc;
                const float* bpp = (lane == 0) ? sr : (S + OF_CX + ii);
                const int    bst = (lane == 0) ? 1 : 12;
                float* gS = (lane == 0) ? (out + O_KS + bt * 6) : (out + O_KSBIG + bt * 72 + ii);
                #pragma unroll
                for (int k = 0; k < 6; ++k) {
                    const float tsum = S[OF_CU + k*4] * x0 + S[OF_CU + k*4 + 1] * x1
                                     + S[OF_CU + k*4 + 2] * x2 + S[OF_CU + k*4 + 3] * x3;
                    const float w2 = (lane == 0) ? S[OF_S + k] : 1.0f;
                    gS[k * gst] = -w1p[k] * (bpp[k * bst] + w2 * tsum);
                }
            }
        }
        __syncthreads();

        // ================= Stage E: Vxx_new, Vx_new, dV/err accumulators =================
        if (lane < 48) {
            const int i = lane >> 2, j0 = (lane & 3) * 3;
            float kcol[4], tq[4], kt[4];
            #pragma unroll
            for (int a2 = 0; a2 < 4; ++a2) { kcol[a2] = sKu[a2 * 12 + i]; tq[a2] = stQux[a2 * 12 + i]; }
            #pragma unroll
            for (int a2 = 0; a2 < 4; ++a2)
                kt[a2] = kcol[0] * q2v[a2] + kcol[1] * q2v[4 + a2] + kcol[2] * q2v[8 + a2] + kcol[3] * q2v[12 + a2];
            #pragma unroll
            for (int d = 0; d < 3; ++d) {
                const int j = j0 + d;
                float acc = 0.5f * (sQxx2[i * 12 + j] + sQxx2[j * 12 + i]);
                #pragma unroll
                for (int a2 = 0; a2 < 4; ++a2) {
                    const float kj = sKu[a2 * 12 + j];
                    acc += tq[a2] * kj + stQux[a2 * 12 + j] * kcol[a2] + kt[a2] * kj;
                }
                sVxx[i * 12 + j] = acc;
            }
        } else if (lane < 60) {
            const int i = lane - 48;
            const float kc0 = sKu[i], kc1 = sKu[12 + i], kc2 = sKu[24 + i], kc3 = sKu[36 + i];
            float acc = sQx2[i] + kc0 * sQu[0] + kc1 * sQu[1] + kc2 * sQu[2] + kc3 * sQu[3];
            #pragma unroll
            for (int a2 = 0; a2 < 4; ++a2) {
                const float kta = kc0 * q2v[a2] + kc1 * q2v[4 + a2] + kc2 * q2v[8 + a2] + kc3 * q2v[12 + a2];
                acc += (kta + stQux[a2 * 12 + i]) * sku[a2];
            }
            sVx[i] = acc;
        } else if (lane == 60) {
            accDV0 += sku[0] * sQu[0] + sku[1] * sQu[1] + sku[2] * sQu[2] + sku[3] * sQu[3];
        } else if (lane == 61) {
            float d = 0.f;
            #pragma unroll
            for (int a2 = 0; a2 < 4; ++a2) {
                float tb = q2v[a2 * 4] * sku[0] + q2v[a2 * 4 + 1] * sku[1]
                         + q2v[a2 * 4 + 2] * sku[2] + q2v[a2 * 4 + 3] * sku[3];
                d += sku[a2] * tb;
            }
            accDV1 += 0.5f * d;
        } else if (lane == 62) {
            float m = fabsf(sQu[0]);
            m = fmaxf(m, fabsf(sQu[1])); m = fmaxf(m, fabsf(sQu[2])); m = fmaxf(m, fabsf(sQu[3]));
            accQE = fmaxf(accQE, m);
        } else {
            float m = 0.f;
            #pragma unroll
            for (int k = 0; k < 6; ++k) m = fmaxf(m, fabsf(sr[k]));
            accME = fmaxf(accME, m);
        }
        wait_vm0();        // next-step staging (and this step's stores) complete
        __syncthreads();   // sVxx/sVx carry visible for next Stage A
        cur ^= 1;
    }

    // ---------- epilogue ----------
    if (lane == 60) out[O_DV + b * 2 + 0] = accDV0;
    if (lane == 61) out[O_DV + b * 2 + 1] = accDV1;
    if (lane == 62) sErr[0] = accQE;
    if (lane == 63) sErr[1] = accME;
    __syncthreads();
    if (lane == 0) ws[b] = fmaxf(sErr[0], sErr[1]);
    if (lane < 12) out[O_VX + b * 12 + lane] = sVx[lane];
    for (int e = lane; e < 144; e += 64) out[O_VXX + (size_t)b * 144 + e] = sVxx[e];
}

__global__ __launch_bounds__(256) void opt_reduce(const float* __restrict__ ws,
                                                  float* __restrict__ out)
{
    float v = ws[threadIdx.x];
    #pragma unroll
    for (int o = 32; o > 0; o >>= 1) v = fmaxf(v, __shfl_down(v, o, 64));
    __shared__ float m[4];
    if ((threadIdx.x & 63) == 0) m[threadIdx.x >> 6] = v;
    __syncthreads();
    if (threadIdx.x == 0) out[O_OPT] = fmaxf(fmaxf(m[0], m[1]), fmaxf(m[2], m[3]));
}

extern "C" void kernel_launch(void* const* d_in, const int* in_sizes, int n_in,
                              void* d_out, int out_size, void* d_ws, size_t ws_size,
                              hipStream_t stream) {
    const float* qx  = (const float*)d_in[0];
    const float* qu  = (const float*)d_in[1];
    const float* qxx = (const float*)d_in[2];
    const float* qxu = (const float*)d_in[3];
    const float* quu = (const float*)d_in[4];
    const float* fx  = (const float*)d_in[5];
    const float* fu  = (const float*)d_in[6];
    const float* fxx = (const float*)d_in[7];
    const float* fxu = (const float*)d_in[8];
    const float* fuu = (const float*)d_in[9];
    const float* cx  = (const float*)d_in[10];
    const float* cu  = (const float*)d_in[11];
    const float* c_  = (const float*)d_in[12];
    const float* s_  = (const float*)d_in[13];
    const float* px  = (const float*)d_in[14];
    const float* pxx = (const float*)d_in[15];
    float* out = (float*)d_out;
    float* ws  = (float*)d_ws;

    hipLaunchKernelGGL(ddp_backward, dim3(B_), dim3(64), 0, stream,
                       qx, qu, qxx, qxu, quu, fx, fu, fxx, fxu, fuu,
                       cx, cu, c_, s_, px, pxx, out, ws);
    hipLaunchKernelGGL(opt_reduce, dim3(1), dim3(256), 0, stream, ws, out);
}

// Round 3
// 858.606 us; speedup vs baseline: 1.0024x; 1.0024x over previous
//
#include <hip/hip_runtime.h>
#include <cstdint>
#include <cstddef>

#define B_  256
#define T_  128

constexpr float MU_F      = 0.1f;
constexpr float REG_FAC_F = (float)(1.6 * 1.6 - 1.0);   // 1.56

typedef float float4v __attribute__((ext_vector_type(4)));

__device__ __forceinline__ float4v splat(float x) { float4v r = {x, x, x, x}; return r; }

// ---- staged small-buffer layout (float offsets within one ring slot) ----
#define SF_FX   0
#define SF_FU   144
#define SF_QXX  192
#define SF_QXU  336
#define SF_QUU  384
#define SF_QX   400
#define SF_QU   412
#define SF_CX   416
#define SF_CU   488
#define SF_C    512
#define SF_S    520
#define STG_N   532     // padded; 532*4 bytes = multiple of 16

// ---- output layout (float offsets into d_out) ----
#define O_KU    0
#define O_KUBIG 131072
#define O_KS    1703936
#define O_KSBIG 1900544
#define O_DV    4259840
#define O_OPT   4260352
#define O_VX    4260353
#define O_VXX   4263425

__global__ __launch_bounds__(64) void ddp_backward(
    const float* __restrict__ qx,  const float* __restrict__ qu,
    const float* __restrict__ qxx, const float* __restrict__ qxu,
    const float* __restrict__ quu, const float* __restrict__ fx,
    const float* __restrict__ fu,  const float* __restrict__ fxx,
    const float* __restrict__ fxu, const float* __restrict__ fuu,
    const float* __restrict__ cx,  const float* __restrict__ cu,
    const float* __restrict__ c_,  const float* __restrict__ s_,
    const float* __restrict__ px,  const float* __restrict__ pxx,
    float* __restrict__ out, float* __restrict__ ws)
{
    const int lane = threadIdx.x;          // one wave per block
    const int b    = blockIdx.x;
    const size_t bt0 = (size_t)b * T_ + (T_ - 1);

    __shared__ __align__(16) float stg[2][STG_N];
    __shared__ __align__(16) float sVxx[144], sfxV[144], sQxx2[144];
    __shared__ __align__(16) float sfuV[48], stQux[48], sKu[48];
    __shared__ __align__(16) float sGuu[16];
    __shared__ float sVx[12], sQxb[12], sQub[4], sQu[4], sQx2[12];
    __shared__ float sr[6], scinv[6], ssc[6], sscr[6];
    __shared__ float sku[4], sErr[2];

    float accDV0 = 0.f, accDV1 = 0.f, accQE = 0.f, accME = 0.f;

    const float* srcs[12] = {qx, qu, qxx, qxu, quu, fx, fu, cx, cu, c_, s_, qx};

    // ---- per-lane gather setup: slots 0..127 cover staged floats [0,512) ----
    // seg:   fx    fu    qxx   qxu   quu  qx   qu   cx    cu
    // slots: 0-35  36-47 48-83 84-95 96-99 100-102 103  104-121 122-127
    const int segStart[10] = {0, 36, 48, 84, 96, 100, 103, 104, 122, 128};
    const int segArr[9]    = {5, 6, 2, 3, 4, 0, 1, 7, 8};
    const int segStride[9] = {144, 48, 144, 48, 16, 12, 4, 72, 24};

    const float* gp0 = nullptr; int gstr0 = 0;
    const float* gp1 = nullptr; int gstr1 = 0;
    {
        #pragma unroll
        for (int g = 0; g < 9; ++g) {
            if (lane >= segStart[g] && lane < segStart[g + 1]) {
                gp0 = srcs[segArr[g]] + bt0 * (size_t)segStride[g] + (lane - segStart[g]) * 4;
                gstr0 = segStride[g];
            }
            const int s1 = 64 + lane;
            if (s1 >= segStart[g] && s1 < segStart[g + 1]) {
                gp1 = srcs[segArr[g]] + bt0 * (size_t)segStride[g] + (s1 - segStart[g]) * 4;
                gstr1 = segStride[g];
            }
        }
    }
    // tail: c (6 floats) + s (6 floats), lanes 0..11
    const float* tp = (lane < 6) ? (c_ + bt0 * 6 + lane) : (s_ + bt0 * 6 + (lane - 6));
    const int tailLds = (lane < 6) ? (SF_C + lane) : (SF_S + lane - 6);

    // ---- per-lane fxx/fxu/fuu register-slice setup (lanes 0..51) ----
    const float* pfp; int pfStr; int pfSlice;
    if (lane < 36) {
        const int i = lane / 3, j0 = (lane % 3) * 4;
        pfp = fxx + bt0 * 1728 + i * 12 + j0; pfStr = 144; pfSlice = 1728;
    } else if (lane < 48) {
        const int i = lane - 36;
        pfp = fxu + bt0 * 576 + i * 4; pfStr = 48; pfSlice = 576;
    } else if (lane < 52) {
        const int a = lane - 48;
        pfp = fuu + bt0 * 192 + a * 4; pfStr = 16; pfSlice = 192;
    } else {
        pfp = fuu + bt0 * 192; pfStr = 0; pfSlice = 0;  // dummy, never loaded
    }
    float4v pf[12];

    // ---------- prologue: carry init + first staged slice ----------
    for (int e = lane; e < 144; e += 64) sVxx[e] = pxx[(size_t)b * 144 + e];
    if (lane < 12) sVx[lane] = px[(size_t)b * 12 + lane];
    {
        float4v g0 = *(const float4v*)gp0;
        float4v g1 = *(const float4v*)gp1;
        float gt = 0.f;
        if (lane < 12) gt = *tp;
        *(float4v*)&stg[0][4 * lane]       = g0;
        *(float4v*)&stg[0][256 + 4 * lane] = g1;
        if (lane < 12) stg[0][tailLds] = gt;
        if (lane < 52) {
            const float* p = pfp;
            #pragma unroll
            for (int s2 = 0; s2 < 12; ++s2) { pf[s2] = *(const float4v*)p; p += pfStr; }
        }
    }

    int cur = 0;
    for (int t = T_ - 1; t >= 0; --t) {
        const float* S = stg[cur];
        const size_t bt = (size_t)b * T_ + t;

        // issue next-step gather loads (registers; compiler tracks waits)
        float4v g0n, g1n; float gtn = 0.f;
        if (t > 0) {
            gp0 -= gstr0; gp1 -= gstr1;
            g0n = *(const float4v*)gp0;
            g1n = *(const float4v*)gp1;
            if (lane < 12) { tp -= 6; gtn = *tp; }
        }

        // ================= Stage A =================
        if (lane < 36) {                       // sfxV rows, 4 cols per lane
            const int i = lane / 3, k0 = (lane % 3) * 4;
            float4v acc = splat(0.f);
            #pragma unroll
            for (int m = 0; m < 12; ++m)
                acc += splat(S[SF_FX + m * 12 + i]) * (*(const float4v*)&sVxx[m * 12 + k0]);
            *(float4v*)&sfxV[i * 12 + k0] = acc;
        }
        if (lane >= 36 && lane < 48) {         // sfuV
            const int l = lane - 36, a = l / 3, k0 = (l % 3) * 4;
            float4v acc = splat(0.f);
            #pragma unroll
            for (int m = 0; m < 12; ++m)
                acc += splat(S[SF_FU + m * 4 + a]) * (*(const float4v*)&sVxx[m * 12 + k0]);
            *(float4v*)&sfuV[a * 12 + k0] = acc;
        }
        if (lane >= 48 && lane < 54) {         // constraint scalars
            const int k = lane - 48;
            const float cc = S[SF_C + k], sv = S[SF_S + k];
            const float r = sv * cc + MU_F;
            const float ci = 1.0f / cc;
            sr[k] = r; scinv[k] = ci; ssc[k] = sv * ci; sscr[k] = ci * r;
        }
        if (lane >= 54 && lane < 58) {         // Qub
            const int a = lane - 54;
            float acc = S[SF_QU + a];
            #pragma unroll
            for (int k = 0; k < 6; ++k)  acc += S[SF_CU + k * 4 + a] * S[SF_S + k];
            #pragma unroll
            for (int m = 0; m < 12; ++m) acc += S[SF_FU + m * 4 + a] * sVx[m];
            sQub[a] = acc;
        }
        if (lane >= 52) {                      // Qxb
            const int i = lane - 52;
            float acc = S[SF_QX + i];
            #pragma unroll
            for (int k = 0; k < 6; ++k)  acc += S[SF_CX + k * 12 + i] * S[SF_S + k];
            #pragma unroll
            for (int m = 0; m < 12; ++m) acc += S[SF_FX + m * 12 + i] * sVx[m];
            sQxb[i] = acc;
        }

        // ================= Stage B =================
        if (lane < 36) {                       // Qxx2, 4 elements
            const int i = lane / 3, j0 = (lane % 3) * 4;
            float4v e = *(const float4v*)&S[SF_QXX + i * 12 + j0];
            #pragma unroll
            for (int k = 0; k < 12; ++k)
                e += splat(sfxV[i * 12 + k]) * (*(const float4v*)&S[SF_FX + k * 12 + j0]);
            #pragma unroll
            for (int s2 = 0; s2 < 12; ++s2) e += splat(sVx[s2]) * pf[s2];
            #pragma unroll
            for (int k = 0; k < 6; ++k) {
                const float tt = ssc[k] * S[SF_CX + k * 12 + i];
                e -= splat(tt) * (*(const float4v*)&S[SF_CX + k * 12 + j0]);
            }
            *(float4v*)&sQxx2[i * 12 + j0] = e;
        }
        if (lane >= 36 && lane < 48) {         // tempQux, 4 a's per i
            const int i = lane - 36;
            float4v e = *(const float4v*)&S[SF_QXU + i * 4];
            #pragma unroll
            for (int k = 0; k < 12; ++k)
                e += splat(sfxV[i * 12 + k]) * (*(const float4v*)&S[SF_FU + k * 4]);
            #pragma unroll
            for (int s2 = 0; s2 < 12; ++s2) e += splat(sVx[s2]) * pf[s2];
            #pragma unroll
            for (int k = 0; k < 6; ++k) {
                const float tt = ssc[k] * S[SF_CX + k * 12 + i];
                e -= splat(tt) * (*(const float4v*)&S[SF_CU + k * 4]);
            }
            stQux[i]      = e.x;
            stQux[12 + i] = e.y;
            stQux[24 + i] = e.z;
            stQux[36 + i] = e.w;
        }
        if (lane >= 48 && lane < 52) {         // Guu row a
            const int a = lane - 48;
            float4v g = *(const float4v*)&S[SF_QUU + a * 4];
            #pragma unroll
            for (int k = 0; k < 12; ++k)
                g += splat(sfuV[a * 12 + k]) * (*(const float4v*)&S[SF_FU + k * 4]);
            #pragma unroll
            for (int s2 = 0; s2 < 12; ++s2) g += splat(sVx[s2]) * pf[s2];
            #pragma unroll
            for (int k = 0; k < 6; ++k) {
                const float tt = ssc[k] * S[SF_CU + k * 4 + a];
                g -= splat(tt) * (*(const float4v*)&S[SF_CU + k * 4]);
            }
            *(float4v*)&sGuu[a * 4] = g;
        }
        if (lane >= 52 && lane < 56) {         // Qu
            const int a = lane - 52;
            float acc = sQub[a];
            #pragma unroll
            for (int k = 0; k < 6; ++k) acc -= S[SF_CU + k * 4 + a] * sscr[k];
            sQu[a] = acc;
        }
        if (lane >= 52) {                      // Qx2
            const int i = lane - 52;
            float acc = sQxb[i];
            #pragma unroll
            for (int k = 0; k < 6; ++k) acc -= S[SF_CX + k * 12 + i] * sscr[k];
            sQx2[i] = acc;
        }

        // issue next-step pf loads (values just consumed above)
        if (t > 0 && lane < 52) {
            pfp -= pfSlice;
            const float* p = pfp;
            #pragma unroll
            for (int s2 = 0; s2 < 12; ++s2) { pf[s2] = *(const float4v*)p; p += pfStr; }
        }

        // ================= Stage D: symmetrize + LU + 13-RHS solve + K outputs =================
        float q2v[16];
        {
            float m4[16];
            #pragma unroll
            for (int e = 0; e < 16; ++e) {
                const int a = e >> 2, b2 = e & 3;
                const float gv = 0.5f * (sGuu[e] + sGuu[b2 * 4 + a]);
                q2v[e] = gv;
                m4[e]  = gv + S[SF_QUU + e] * REG_FAC_F;
            }
            const float i0  = 1.0f / m4[0];
            const float l10 = m4[4] * i0, l20 = m4[8] * i0, l30 = m4[12] * i0;
            float a11 = m4[5]  - l10 * m4[1], a12 = m4[6]  - l10 * m4[2], a13 = m4[7]  - l10 * m4[3];
            float a21 = m4[9]  - l20 * m4[1], a22 = m4[10] - l20 * m4[2], a23 = m4[11] - l20 * m4[3];
            float a31 = m4[13] - l30 * m4[1], a32 = m4[14] - l30 * m4[2], a33 = m4[15] - l30 * m4[3];
            const float i1  = 1.0f / a11;
            const float l21 = a21 * i1, l31 = a31 * i1;
            a22 -= l21 * a12; a23 -= l21 * a13;
            a32 -= l31 * a12; a33 -= l31 * a13;
            const float i2  = 1.0f / a22;
            const float l32 = a32 * i2;
            a33 -= l32 * a23;

            if (lane < 13) {
                const int ii = (lane == 0) ? 0 : (lane - 1);
                float r0, r1, r2, r3;
                if (lane == 0) { r0 = sQu[0]; r1 = sQu[1]; r2 = sQu[2]; r3 = sQu[3]; }
                else { r0 = stQux[ii]; r1 = stQux[12 + ii]; r2 = stQux[24 + ii]; r3 = stQux[36 + ii]; }
                const float y0 = r0;
                const float y1 = r1 - l10 * y0;
                const float y2 = r2 - l20 * y0 - l21 * y1;
                const float y3 = r3 - l30 * y0 - l31 * y1 - l32 * y2;
                float x3 = y3 / a33;
                float x2 = (y2 - a23 * x3) * i2;
                float x1 = (y1 - a12 * x2 - a13 * x3) * i1;
                float x0 = (y0 - m4[1] * x1 - m4[2] * x2 - m4[3] * x3) * i0;
                x0 = -x0; x1 = -x1; x2 = -x2; x3 = -x3;

                const int gst = (lane == 0) ? 1 : 12;
                float* lK = (lane == 0) ? sku : (sKu + ii);
                lK[0] = x0; lK[gst] = x1; lK[2 * gst] = x2; lK[3 * gst] = x3;
                float* gK = (lane == 0) ? (out + O_KU + bt * 4) : (out + O_KUBIG + bt * 48 + ii);
                gK[0] = x0; gK[gst] = x1; gK[2 * gst] = x2; gK[3 * gst] = x3;

                const float* w1p = (lane == 0) ? scinv : ssc;
                float* gS = (lane == 0) ? (out + O_KS + bt * 6) : (out + O_KSBIG + bt * 72 + ii);
                #pragma unroll
                for (int k = 0; k < 6; ++k) {
                    const float tsum = S[SF_CU + k * 4] * x0 + S[SF_CU + k * 4 + 1] * x1
                                     + S[SF_CU + k * 4 + 2] * x2 + S[SF_CU + k * 4 + 3] * x3;
                    const float bv = (lane == 0) ? sr[k] : S[SF_CX + k * 12 + ii];
                    const float w2 = (lane == 0) ? S[SF_S + k] : 1.0f;
                    gS[k * gst] = -w1p[k] * (bv + w2 * tsum);
                }
            }
        }

        // ================= Stage E: Vxx_new, Vx_new, accumulators =================
        if (lane < 48) {
            const int i = lane >> 2, j0 = (lane & 3) * 3;
            float kcol[4], tq[4], kt[4];
            #pragma unroll
            for (int a2 = 0; a2 < 4; ++a2) { kcol[a2] = sKu[a2 * 12 + i]; tq[a2] = stQux[a2 * 12 + i]; }
            #pragma unroll
            for (int a2 = 0; a2 < 4; ++a2)
                kt[a2] = kcol[0] * q2v[a2] + kcol[1] * q2v[4 + a2] + kcol[2] * q2v[8 + a2] + kcol[3] * q2v[12 + a2];
            #pragma unroll
            for (int d = 0; d < 3; ++d) {
                const int j = j0 + d;
                float acc = 0.5f * (sQxx2[i * 12 + j] + sQxx2[j * 12 + i]);
                #pragma unroll
                for (int a2 = 0; a2 < 4; ++a2) {
                    const float kj = sKu[a2 * 12 + j];
                    acc += tq[a2] * kj + stQux[a2 * 12 + j] * kcol[a2] + kt[a2] * kj;
                }
                sVxx[i * 12 + j] = acc;
            }
        } else if (lane < 60) {
            const int i = lane - 48;
            const float kc0 = sKu[i], kc1 = sKu[12 + i], kc2 = sKu[24 + i], kc3 = sKu[36 + i];
            float acc = sQx2[i] + kc0 * sQu[0] + kc1 * sQu[1] + kc2 * sQu[2] + kc3 * sQu[3];
            #pragma unroll
            for (int a2 = 0; a2 < 4; ++a2) {
                const float kta = kc0 * q2v[a2] + kc1 * q2v[4 + a2] + kc2 * q2v[8 + a2] + kc3 * q2v[12 + a2];
                acc += (kta + stQux[a2 * 12 + i]) * sku[a2];
            }
            sVx[i] = acc;
        } else if (lane == 60) {
            accDV0 += sku[0] * sQu[0] + sku[1] * sQu[1] + sku[2] * sQu[2] + sku[3] * sQu[3];
        } else if (lane == 61) {
            float d = 0.f;
            #pragma unroll
            for (int a2 = 0; a2 < 4; ++a2) {
                float tb = q2v[a2 * 4] * sku[0] + q2v[a2 * 4 + 1] * sku[1]
                         + q2v[a2 * 4 + 2] * sku[2] + q2v[a2 * 4 + 3] * sku[3];
                d += sku[a2] * tb;
            }
            accDV1 += 0.5f * d;
        } else if (lane == 62) {
            float m = fabsf(sQu[0]);
            m = fmaxf(m, fabsf(sQu[1])); m = fmaxf(m, fabsf(sQu[2])); m = fmaxf(m, fabsf(sQu[3]));
            accQE = fmaxf(accQE, m);
        } else {
            float m = 0.f;
            #pragma unroll
            for (int k = 0; k < 6; ++k) m = fmaxf(m, fabsf(sr[k]));
            accME = fmaxf(accME, m);
        }

        // commit next-step staged slice into the other ring slot
        if (t > 0) {
            float* D = stg[cur ^ 1];
            *(float4v*)&D[4 * lane]       = g0n;
            *(float4v*)&D[256 + 4 * lane] = g1n;
            if (lane < 12) D[tailLds] = gtn;
        }
        cur ^= 1;
    }

    // ---------- epilogue ----------
    if (lane == 60) out[O_DV + b * 2 + 0] = accDV0;
    if (lane == 61) out[O_DV + b * 2 + 1] = accDV1;
    if (lane == 62) sErr[0] = accQE;
    if (lane == 63) sErr[1] = accME;
    __syncthreads();
    if (lane == 0) ws[b] = fmaxf(sErr[0], sErr[1]);
    if (lane < 12) out[O_VX + b * 12 + lane] = sVx[lane];
    for (int e = lane; e < 144; e += 64) out[O_VXX + (size_t)b * 144 + e] = sVxx[e];
}

__global__ __launch_bounds__(256) void opt_reduce(const float* __restrict__ ws,
                                                  float* __restrict__ out)
{
    float v = ws[threadIdx.x];
    #pragma unroll
    for (int o = 32; o > 0; o >>= 1) v = fmaxf(v, __shfl_down(v, o, 64));
    __shared__ float m[4];
    if ((threadIdx.x & 63) == 0) m[threadIdx.x >> 6] = v;
    __syncthreads();
    if (threadIdx.x == 0) out[O_OPT] = fmaxf(fmaxf(m[0], m[1]), fmaxf(m[2], m[3]));
}

extern "C" void kernel_launch(void* const* d_in, const int* in_sizes, int n_in,
                              void* d_out, int out_size, void* d_ws, size_t ws_size,
                              hipStream_t stream) {
    const float* qx  = (const float*)d_in[0];
    const float* qu  = (const float*)d_in[1];
    const float* qxx = (const float*)d_in[2];
    const float* qxu = (const float*)d_in[3];
    const float* quu = (const float*)d_in[4];
    const float* fx  = (const float*)d_in[5];
    const float* fu  = (const float*)d_in[6];
    const float* fxx = (const float*)d_in[7];
    const float* fxu = (const float*)d_in[8];
    const float* fuu = (const float*)d_in[9];
    const float* cx  = (const float*)d_in[10];
    const float* cu  = (const float*)d_in[11];
    const float* c_  = (const float*)d_in[12];
    const float* s_  = (const float*)d_in[13];
    const float* px  = (const float*)d_in[14];
    const float* pxx = (const float*)d_in[15];
    float* out = (float*)d_out;
    float* ws  = (float*)d_ws;

    hipLaunchKernelGGL(ddp_backward, dim3(B_), dim3(64), 0, stream,
                       qx, qu, qxx, qxu, quu, fx, fu, fxx, fxu, fuu,
                       cx, cu, c_, s_, px, pxx, out, ws);
    hipLaunchKernelGGL(opt_reduce, dim3(1), dim3(256), 0, stream, ws, out);
}